// Round 3
// baseline (340.228 us; speedup 1.0000x reference)
//
#include <hip/hip_runtime.h>
#include <cstdint>
#include <cstddef>

typedef __bf16 bf16;
typedef __bf16 bf16x8 __attribute__((ext_vector_type(8)));
typedef __bf16 bf16x4 __attribute__((ext_vector_type(4)));
typedef _Float16 f16;
typedef _Float16 f16x4 __attribute__((ext_vector_type(4)));
typedef _Float16 f16x8 __attribute__((ext_vector_type(8)));
typedef __fp16 fp16x2 __attribute__((ext_vector_type(2)));
typedef float f32x4 __attribute__((ext_vector_type(4)));

#define DEV static __device__ __forceinline__
#if __has_builtin(__builtin_amdgcn_exp2f)
#define EXP2(x) __builtin_amdgcn_exp2f(x)
#else
#define EXP2(x) exp2f(x)
#endif
#define QSCALE 0.18033688011112042f

DEV float gelu_exact(float v) {
  return 0.5f * v * (1.0f + erff(v * 0.70710678118654752f));
}

// ---------------- coalesced weight transpose: W[K,N] fp32 -> Wt[N,K] bf16 ---
// blocks 0..159: 64x64 weight transpose tiles. blocks 160..2207: x fp32->bf16.
__global__ void cvt_w_kernel(const float* __restrict__ qkv_w, bf16* __restrict__ qwt,
                             const float* __restrict__ proj_w, bf16* __restrict__ pwt,
                             const float* __restrict__ f1w, bf16* __restrict__ f1wt,
                             const float* __restrict__ f2w, bf16* __restrict__ f2wt,
                             const float* __restrict__ x, bf16* __restrict__ xb) {
  int blk = blockIdx.x;
  const int tid = threadIdx.x;
  if (blk >= 160) {  // x conversion: 2048 blocks x 2048 elems
    const size_t i = ((size_t)(blk - 160) * 256 + tid) * 8;
    const float4 a0 = *(const float4*)(x + i);
    const float4 a1 = *(const float4*)(x + i + 4);
    bf16x8 v;
    v[0] = (bf16)a0.x; v[1] = (bf16)a0.y; v[2] = (bf16)a0.z; v[3] = (bf16)a0.w;
    v[4] = (bf16)a1.x; v[5] = (bf16)a1.y; v[6] = (bf16)a1.z; v[7] = (bf16)a1.w;
    *(bf16x8*)(xb + i) = v;
    return;
  }
  const float* w; bf16* o; int K, N;
  if (blk < 48)       { w = qkv_w;  o = qwt;  K = 256; N = 768; }
  else if (blk < 64)  { w = proj_w; o = pwt;  K = 256; N = 256; blk -= 48; }
  else if (blk < 112) { w = f1w;    o = f1wt; K = 256; N = 768; blk -= 64; }
  else                { w = f2w;    o = f2wt; K = 768; N = 256; blk -= 112; }
  const int ntiles = N >> 6;
  const int kt = blk / ntiles, nt = blk - kt * ntiles;
  const int k0 = kt * 64, n0 = nt * 64;
  __shared__ float tile[64][65];
#pragma unroll
  for (int j = 0; j < 4; ++j) {  // load: 1024 float4 chunks, coalesced rows
    const int c = j * 256 + tid;
    const int row = c >> 4, c4 = (c & 15) * 4;
    const float4 v = *(const float4*)(w + (size_t)(k0 + row) * N + n0 + c4);
    tile[row][c4] = v.x; tile[row][c4 + 1] = v.y;
    tile[row][c4 + 2] = v.z; tile[row][c4 + 3] = v.w;
  }
  __syncthreads();
#pragma unroll
  for (int j = 0; j < 4; ++j) {  // store: 1024 bf16x4 chunks, coalesced rows
    const int c = j * 256 + tid;
    const int n = c >> 4, k4 = (c & 15) * 4;
    bf16x4 ov;
#pragma unroll
    for (int i = 0; i < 4; ++i) ov[i] = (bf16)tile[k4 + i][n];
    *(bf16x4*)(o + (size_t)(n0 + n) * K + k0 + k4) = ov;
  }
}

// ---------------- QKV GEMM (bf16 A) with reg-prefetch staging (T14) ---------
__global__ __launch_bounds__(256, 3)
void gemm_qkv_kernel(const bf16* __restrict__ A, const bf16* __restrict__ Wt,
                     const float* __restrict__ bias, bf16* __restrict__ qb,
                     bf16* __restrict__ kb, f16* __restrict__ vt) {
  const int tid = threadIdx.x;
  const int wave = tid >> 6, lane = tid & 63;
  const int quad = lane >> 4, l15 = lane & 15;
  const int m0 = blockIdx.y * 128, n0 = blockIdx.x * 128;
  const int mw = (wave >> 1) * 64, nw = (wave & 1) * 64;
  const int K = 256;

  __shared__ bf16 lA[128 * 72];
  __shared__ bf16 lB[128 * 72];

  f32x4 acc[4][4] = {};
  uint4 pa4[4], pb4[4];

  // prologue: tile 0 into regs
#pragma unroll
  for (int j = 0; j < 4; ++j) {
    const int c = j * 256 + tid;
    const int row = c >> 3, kc = (c & 7) * 8;
    pa4[j] = *(const uint4*)(A + (size_t)(m0 + row) * K + kc);
    pb4[j] = *(const uint4*)(Wt + (size_t)(n0 + row) * K + kc);
  }

  for (int k0 = 0; k0 < K; k0 += 64) {
    __syncthreads();
#pragma unroll
    for (int j = 0; j < 4; ++j) {
      const int c = j * 256 + tid;
      const int row = c >> 3, kc = (c & 7) * 8;
      *(uint4*)(lA + row * 72 + kc) = pa4[j];
      *(uint4*)(lB + row * 72 + kc) = pb4[j];
    }
    __syncthreads();
    if (k0 + 64 < K) {
#pragma unroll
      for (int j = 0; j < 4; ++j) {
        const int c = j * 256 + tid;
        const int row = c >> 3, kc = (c & 7) * 8;
        pa4[j] = *(const uint4*)(A + (size_t)(m0 + row) * K + k0 + 64 + kc);
        pb4[j] = *(const uint4*)(Wt + (size_t)(n0 + row) * K + k0 + 64 + kc);
      }
    }
#pragma unroll
    for (int ks = 0; ks < 2; ++ks) {
      bf16x8 af[4], bfm[4];
#pragma unroll
      for (int i = 0; i < 4; ++i)
        af[i] = *(const bf16x8*)(lA + (mw + i * 16 + l15) * 72 + ks * 32 + quad * 8);
#pragma unroll
      for (int j = 0; j < 4; ++j)
        bfm[j] = *(const bf16x8*)(lB + (nw + j * 16 + l15) * 72 + ks * 32 + quad * 8);
#pragma unroll
      for (int i = 0; i < 4; ++i)
#pragma unroll
        for (int j = 0; j < 4; ++j)
          acc[i][j] = __builtin_amdgcn_mfma_f32_16x16x32_bf16(af[i], bfm[j],
                                                              acc[i][j], 0, 0, 0);
    }
  }

  const bool isV = (n0 >= 512);
#pragma unroll
  for (int i = 0; i < 4; ++i) {
#pragma unroll
    for (int j = 0; j < 4; ++j) {
      const int n = n0 + nw + j * 16 + l15;
      const float bs = bias[n];
      if (isV) {
        const int m = m0 + mw + i * 16 + quad * 4;
        const int b = m >> 12, t = m & 4095;
        const int h = (n >> 6) & 3, d = n & 63;
        const int tp = (t & ~31) | (((t >> 2) & 3) << 3) | (((t >> 4) & 1) << 2);
        f16x4 hv;
#pragma unroll
        for (int r = 0; r < 4; ++r) hv[r] = (f16)(acc[i][j][r] + bs);
        *(f16x4*)(vt + (size_t)((b * 4 + h) * 64 + d) * 4096 + tp) = hv;
      } else {
        const int s = n >> 8, cc = n & 255, h = cc >> 6, d = cc & 63;
#pragma unroll
        for (int r = 0; r < 4; ++r) {
          const int m = m0 + mw + i * 16 + quad * 4 + r;
          const int b = m >> 12, t = m & 4095;
          const float v = acc[i][j][r] + bs;
          const size_t idx = (size_t)((b * 4 + h) * 4096 + t) * 64 + d;
          if (s == 0) qb[idx] = (bf16)(v * QSCALE);
          else        kb[idx] = (bf16)v;
        }
      }
    }
  }
}

// ---------------- flash attention: KV-split (z=2), R2 structure -------------
__global__ __launch_bounds__(256, 2)
void attn_kernel(const bf16* __restrict__ q, const bf16* __restrict__ k,
                 const f16* __restrict__ vt, bf16* __restrict__ o0,
                 bf16* __restrict__ o1, float* __restrict__ pD) {
  const int tid = threadIdx.x;
  const int wave = tid >> 6, lane = tid & 63;
  const int quad = lane >> 4, l15 = lane & 15;
  const int bh = blockIdx.y;
  const int q0 = blockIdx.x * 128;
  const int z = blockIdx.z;
  const int kvbase = z * 2048;
  __shared__ bf16 lK[2][64 * 72];
  __shared__ f16  lV[2][64 * 72];

  bf16x8 qa0[2], qa1[2];
#pragma unroll
  for (int s = 0; s < 2; ++s) {
    const bf16* qp =
        q + ((size_t)bh * 4096 + q0 + wave * 32 + s * 16 + l15) * 64 + quad * 8;
    qa0[s] = *(const bf16x8*)(qp);
    qa1[s] = *(const bf16x8*)(qp + 32);
  }

  const int row0 = tid >> 3, off = (tid & 7) * 8;
  const bf16* kp = k + ((size_t)bh * 4096 + kvbase + row0) * 64 + off;
  const f16*  vp = vt + ((size_t)bh * 64 + row0) * 4096 + kvbase + off;
  const int lidx = row0 * 72 + off;

  *(uint4*)(lK[0] + lidx)            = *(const uint4*)(kp);
  *(uint4*)(lK[0] + lidx + 32 * 72)  = *(const uint4*)(kp + 32 * 64);
  *(uint4*)(lV[0] + lidx)            = *(const uint4*)(vp);
  *(uint4*)(lV[0] + lidx + 32 * 72)  = *(const uint4*)(vp + 32 * 4096);

  f32x4 accO[2][4] = {};
  f32x4 accD[2] = {};
  const f16x8 vone8 = {(f16)1.0f, (f16)1.0f, (f16)1.0f, (f16)1.0f,
                       (f16)1.0f, (f16)1.0f, (f16)1.0f, (f16)1.0f};
  uint4 pk0, pk1, pv0, pv1;

  for (int it = 0; it < 32; ++it) {
    const int cur = it & 1;
    if (it + 1 < 32) {
      const bf16* kn = kp + (size_t)(it + 1) * 64 * 64;
      const f16*  vn = vp + (it + 1) * 64;
      pk0 = *(const uint4*)(kn);
      pk1 = *(const uint4*)(kn + 32 * 64);
      pv0 = *(const uint4*)(vn);
      pv1 = *(const uint4*)(vn + 32 * 4096);
    }
    __syncthreads();

    f32x4 sf[2][4];
    __builtin_amdgcn_s_setprio(1);
#pragma unroll
    for (int c = 0; c < 4; ++c) {
      const bf16x8 kb0 = *(const bf16x8*)(lK[cur] + (c * 16 + l15) * 72 + quad * 8);
      const bf16x8 kb1 = *(const bf16x8*)(lK[cur] + (c * 16 + l15) * 72 + 32 + quad * 8);
#pragma unroll
      for (int s = 0; s < 2; ++s) {
        f32x4 t = {};
        t = __builtin_amdgcn_mfma_f32_16x16x32_bf16(kb0, qa0[s], t, 0, 0, 0);
        t = __builtin_amdgcn_mfma_f32_16x16x32_bf16(kb1, qa1[s], t, 0, 0, 0);
        sf[s][c] = t;
      }
    }
    __builtin_amdgcn_s_setprio(0);

    f16x8 pa[2][2];
#pragma unroll
    for (int s = 0; s < 2; ++s)
#pragma unroll
      for (int c2 = 0; c2 < 2; ++c2) {
        union { fp16x2 h2[4]; f16x8 h8; } u;
        u.h2[0] = __builtin_amdgcn_cvt_pkrtz(EXP2(sf[s][2 * c2][0]),
                                             EXP2(sf[s][2 * c2][1]));
        u.h2[1] = __builtin_amdgcn_cvt_pkrtz(EXP2(sf[s][2 * c2][2]),
                                             EXP2(sf[s][2 * c2][3]));
        u.h2[2] = __builtin_amdgcn_cvt_pkrtz(EXP2(sf[s][2 * c2 + 1][0]),
                                             EXP2(sf[s][2 * c2 + 1][1]));
        u.h2[3] = __builtin_amdgcn_cvt_pkrtz(EXP2(sf[s][2 * c2 + 1][2]),
                                             EXP2(sf[s][2 * c2 + 1][3]));
        pa[s][c2] = u.h8;
      }

    __builtin_amdgcn_s_setprio(1);
#pragma unroll
    for (int s = 0; s < 2; ++s)
#pragma unroll
      for (int c2 = 0; c2 < 2; ++c2)
        accD[s] = __builtin_amdgcn_mfma_f32_16x16x32_f16(pa[s][c2], vone8,
                                                         accD[s], 0, 0, 0);

#pragma unroll
    for (int c2 = 0; c2 < 2; ++c2) {
#pragma unroll
      for (int n = 0; n < 4; ++n) {
        const f16x8 vb =
            *(const f16x8*)(lV[cur] + (n * 16 + l15) * 72 + c2 * 32 + quad * 8);
#pragma unroll
        for (int s = 0; s < 2; ++s)
          accO[s][n] = __builtin_amdgcn_mfma_f32_16x16x32_f16(pa[s][c2], vb,
                                                              accO[s][n], 0, 0, 0);
      }
    }
    __builtin_amdgcn_s_setprio(0);

    if (it + 1 < 32) {
      *(uint4*)(lK[cur ^ 1] + lidx)           = pk0;
      *(uint4*)(lK[cur ^ 1] + lidx + 32 * 72) = pk1;
      *(uint4*)(lV[cur ^ 1] + lidx)           = pv0;
      *(uint4*)(lV[cur ^ 1] + lidx + 32 * 72) = pv1;
    }
  }

  bf16* po = z ? o1 : o0;
  const int b = bh >> 2, h = bh & 3;
#pragma unroll
  for (int s = 0; s < 2; ++s) {
    float inv[4];
#pragma unroll
    for (int r = 0; r < 4; ++r) inv[r] = 1.0f / accD[s][r];
#pragma unroll
    for (int r = 0; r < 4; ++r) {
      const int t = q0 + wave * 32 + s * 16 + quad * 4 + r;
      if (l15 == 0) pD[(size_t)(z * 16 + bh) * 4096 + t] = accD[s][r];
#pragma unroll
      for (int n = 0; n < 4; ++n)
        po[(size_t)(b * 4096 + t) * 256 + h * 64 + n * 16 + l15] =
            (bf16)(accO[s][n][r] * inv[r]);
    }
  }
}

// ---------------- FFN1: bf16-A GEMM + gelu, reg-prefetch staging ------------
__global__ __launch_bounds__(256, 3)
void gemm_ffn1_kernel(const bf16* __restrict__ A, const bf16* __restrict__ Wt,
                      const float* __restrict__ bias, bf16* __restrict__ ob) {
  const int tid = threadIdx.x;
  const int wave = tid >> 6, lane = tid & 63;
  const int quad = lane >> 4, l15 = lane & 15;
  const int m0 = blockIdx.y * 128, n0 = blockIdx.x * 128;
  const int mw = (wave >> 1) * 64, nw = (wave & 1) * 64;
  const int K = 256;

  __shared__ bf16 lA[128 * 72];
  __shared__ bf16 lB[128 * 72];

  f32x4 acc[4][4] = {};
  uint4 pa4[4], pb4[4];

#pragma unroll
  for (int j = 0; j < 4; ++j) {
    const int c = j * 256 + tid;
    const int row = c >> 3, kc = (c & 7) * 8;
    pa4[j] = *(const uint4*)(A + (size_t)(m0 + row) * K + kc);
    pb4[j] = *(const uint4*)(Wt + (size_t)(n0 + row) * K + kc);
  }

  for (int k0 = 0; k0 < K; k0 += 64) {
    __syncthreads();
#pragma unroll
    for (int j = 0; j < 4; ++j) {
      const int c = j * 256 + tid;
      const int row = c >> 3, kc = (c & 7) * 8;
      *(uint4*)(lA + row * 72 + kc) = pa4[j];
      *(uint4*)(lB + row * 72 + kc) = pb4[j];
    }
    __syncthreads();
    if (k0 + 64 < K) {
#pragma unroll
      for (int j = 0; j < 4; ++j) {
        const int c = j * 256 + tid;
        const int row = c >> 3, kc = (c & 7) * 8;
        pa4[j] = *(const uint4*)(A + (size_t)(m0 + row) * K + k0 + 64 + kc);
        pb4[j] = *(const uint4*)(Wt + (size_t)(n0 + row) * K + k0 + 64 + kc);
      }
    }
#pragma unroll
    for (int ks = 0; ks < 2; ++ks) {
      bf16x8 af[4], bfm[4];
#pragma unroll
      for (int i = 0; i < 4; ++i)
        af[i] = *(const bf16x8*)(lA + (mw + i * 16 + l15) * 72 + ks * 32 + quad * 8);
#pragma unroll
      for (int j = 0; j < 4; ++j)
        bfm[j] = *(const bf16x8*)(lB + (nw + j * 16 + l15) * 72 + ks * 32 + quad * 8);
#pragma unroll
      for (int i = 0; i < 4; ++i)
#pragma unroll
        for (int j = 0; j < 4; ++j)
          acc[i][j] = __builtin_amdgcn_mfma_f32_16x16x32_bf16(af[i], bfm[j],
                                                              acc[i][j], 0, 0, 0);
    }
  }

#pragma unroll
  for (int i = 0; i < 4; ++i) {
#pragma unroll
    for (int j = 0; j < 4; ++j) {
      const int n = n0 + nw + j * 16 + l15;
      const float bs = bias[n];
#pragma unroll
      for (int r = 0; r < 4; ++r) {
        const int m = m0 + mw + i * 16 + quad * 4 + r;
        ob[(size_t)m * 768 + n] = (bf16)gelu_exact(acc[i][j][r] + bs);
      }
    }
  }
}

// ---------------- GEMM + bias + residual + LayerNorm fused ------------------
// 32-row x 256-col tile (full LN rows), grid M/32 = 512. Reg-prefetch staging.
// COMBINE: A = denominator-weighted average of two attention partials.
template <int KTILES, bool COMBINE, bool RESID_BF16, bool WRITE_F, bool WRITE_B>
__global__ __launch_bounds__(256, 3)
void gemm_ln_kernel(const bf16* __restrict__ A, const bf16* __restrict__ A2,
                    const float* __restrict__ pD, const bf16* __restrict__ Wt,
                    const float* __restrict__ bias, const void* __restrict__ Rv,
                    const float* __restrict__ lw, const float* __restrict__ lb,
                    float* __restrict__ outf, bf16* __restrict__ outb) {
  const int tid = threadIdx.x;
  const int wave = tid >> 6, lane = tid & 63;
  const int quad = lane >> 4, l15 = lane & 15;
  const int m0 = blockIdx.x * 32;
  const int nw = wave * 64;
  const int K = KTILES * 64;
  __shared__ bf16 lA[32 * 72];
  __shared__ bf16 lB[256 * 72];
  __shared__ float lnsum[4][32];
  __shared__ float lnsq[4][32];
  __shared__ float lnstat[32][2];
  f32x4 acc[2][4] = {};

  const int arow = tid >> 3, akc = (tid & 7) * 8;
  const int am = m0 + arow;
  const int ab = am >> 12, at = am & 4095;

  uint4 pb[8];
  bf16x8 pa0, pa1;
  float pd0 = 0.f, pd1 = 0.f;

  // prologue: tile 0 into regs
  {
    if constexpr (COMBINE) {
      const int h = akc >> 6;
      pa0 = *(const bf16x8*)(A  + (size_t)am * K + akc);
      pa1 = *(const bf16x8*)(A2 + (size_t)am * K + akc);
      pd0 = pD[(size_t)(ab * 4 + h) * 4096 + at];
      pd1 = pD[(size_t)(16 + ab * 4 + h) * 4096 + at];
    } else {
      pa0 = *(const bf16x8*)(A + (size_t)am * K + akc);
    }
#pragma unroll
    for (int j = 0; j < 8; ++j) {
      const int c = j * 256 + tid;
      const int row = c >> 3, kc = (c & 7) * 8;
      pb[j] = *(const uint4*)(Wt + (size_t)row * K + kc);
    }
  }

  for (int kt = 0; kt < KTILES; ++kt) {
    const int k0 = kt * 64;
    __syncthreads();
    // write phase
    if constexpr (COMBINE) {
      const float ws = 1.0f / (pd0 + pd1);
      const float w0 = pd0 * ws, w1 = pd1 * ws;
      bf16x8 cv;
#pragma unroll
      for (int i = 0; i < 8; ++i)
        cv[i] = (bf16)((float)pa0[i] * w0 + (float)pa1[i] * w1);
      *(bf16x8*)(lA + arow * 72 + akc) = cv;
    } else {
      *(bf16x8*)(lA + arow * 72 + akc) = pa0;
    }
#pragma unroll
    for (int j = 0; j < 8; ++j) {
      const int c = j * 256 + tid;
      const int row = c >> 3, kc = (c & 7) * 8;
      *(uint4*)(lB + row * 72 + kc) = pb[j];
    }
    __syncthreads();
    // prefetch next tile
    if (kt + 1 < KTILES) {
      const int kn = k0 + 64;
      if constexpr (COMBINE) {
        const int h = (kn + akc) >> 6;
        pa0 = *(const bf16x8*)(A  + (size_t)am * K + kn + akc);
        pa1 = *(const bf16x8*)(A2 + (size_t)am * K + kn + akc);
        pd0 = pD[(size_t)(ab * 4 + h) * 4096 + at];
        pd1 = pD[(size_t)(16 + ab * 4 + h) * 4096 + at];
      } else {
        pa0 = *(const bf16x8*)(A + (size_t)am * K + kn + akc);
      }
#pragma unroll
      for (int j = 0; j < 8; ++j) {
        const int c = j * 256 + tid;
        const int row = c >> 3, kc = (c & 7) * 8;
        pb[j] = *(const uint4*)(Wt + (size_t)row * K + kn + kc);
      }
    }
#pragma unroll
    for (int ks = 0; ks < 2; ++ks) {
      bf16x8 af[2], bfm[4];
#pragma unroll
      for (int i = 0; i < 2; ++i)
        af[i] = *(const bf16x8*)(lA + (i * 16 + l15) * 72 + ks * 32 + quad * 8);
#pragma unroll
      for (int j = 0; j < 4; ++j)
        bfm[j] = *(const bf16x8*)(lB + (nw + j * 16 + l15) * 72 + ks * 32 + quad * 8);
#pragma unroll
      for (int i = 0; i < 2; ++i)
#pragma unroll
        for (int j = 0; j < 4; ++j)
          acc[i][j] = __builtin_amdgcn_mfma_f32_16x16x32_bf16(af[i], bfm[j],
                                                              acc[i][j], 0, 0, 0);
    }
  }

  float bv[4], lwv[4], lbv[4];
#pragma unroll
  for (int j = 0; j < 4; ++j) {
    const int col = nw + 16 * j + l15;
    bv[j] = bias[col]; lwv[j] = lw[col]; lbv[j] = lb[col];
  }
#pragma unroll
  for (int i = 0; i < 2; ++i) {
    float ps[4] = {}, pq[4] = {};
#pragma unroll
    for (int j = 0; j < 4; ++j) {
#pragma unroll
      for (int r = 0; r < 4; ++r) {
        const int m = m0 + 16 * i + 4 * quad + r;
        const size_t ri = (size_t)m * 256 + nw + 16 * j + l15;
        const float rv = RESID_BF16 ? (float)((const bf16*)Rv)[ri]
                                    : ((const float*)Rv)[ri];
        const float v = acc[i][j][r] + bv[j] + rv;
        acc[i][j][r] = v;
        ps[r] += v;
        pq[r] += v * v;
      }
    }
#pragma unroll
    for (int r = 0; r < 4; ++r) {
#pragma unroll
      for (int mm = 1; mm < 16; mm <<= 1) {
        ps[r] += __shfl_xor(ps[r], mm, 64);
        pq[r] += __shfl_xor(pq[r], mm, 64);
      }
      if (l15 == 0) {
        lnsum[wave][16 * i + 4 * quad + r] = ps[r];
        lnsq[wave][16 * i + 4 * quad + r] = pq[r];
      }
    }
  }
  __syncthreads();
  if (tid < 32) {
    const float s = lnsum[0][tid] + lnsum[1][tid] + lnsum[2][tid] + lnsum[3][tid];
    const float sq = lnsq[0][tid] + lnsq[1][tid] + lnsq[2][tid] + lnsq[3][tid];
    const float mean = s * (1.0f / 256.0f);
    const float var = sq * (1.0f / 256.0f) - mean * mean;
    lnstat[tid][0] = mean;
    lnstat[tid][1] = rsqrtf(var + 1e-5f);
  }
  __syncthreads();
#pragma unroll
  for (int i = 0; i < 2; ++i) {
#pragma unroll
    for (int r = 0; r < 4; ++r) {
      const int row = 16 * i + 4 * quad + r;
      const float mean = lnstat[row][0], rstd = lnstat[row][1];
#pragma unroll
      for (int j = 0; j < 4; ++j) {
        const float ov = (acc[i][j][r] - mean) * rstd * lwv[j] + lbv[j];
        const size_t gi = (size_t)(m0 + row) * 256 + nw + 16 * j + l15;
        if constexpr (WRITE_F) outf[gi] = ov;
        if constexpr (WRITE_B) outb[gi] = (bf16)ov;
      }
    }
  }
}

extern "C" void kernel_launch(void* const* d_in, const int* in_sizes, int n_in,
                              void* d_out, int out_size, void* d_ws, size_t ws_size,
                              hipStream_t stream) {
  const float* x      = (const float*)d_in[0];
  const float* qkv_w  = (const float*)d_in[1];
  const float* qkv_b  = (const float*)d_in[2];
  const float* proj_w = (const float*)d_in[3];
  const float* proj_b = (const float*)d_in[4];
  const float* n1_w   = (const float*)d_in[5];
  const float* n1_b   = (const float*)d_in[6];
  const float* ffn_w1 = (const float*)d_in[7];
  const float* ffn_b1 = (const float*)d_in[8];
  const float* ffn_w2 = (const float*)d_in[9];
  const float* ffn_b2 = (const float*)d_in[10];
  const float* n2_w   = (const float*)d_in[11];
  const float* n2_b   = (const float*)d_in[12];
  float* out = (float*)d_out;

  char* ws = (char*)d_ws;
  bf16*  qwt  = (bf16*)(ws + 0);
  bf16*  pwt  = (bf16*)(ws + 393216);
  bf16*  f1wt = (bf16*)(ws + 524288);
  bf16*  f2wt = (bf16*)(ws + 917504);
  bf16*  qb   = (bf16*)(ws + 1310720);
  bf16*  kb   = (bf16*)(ws + 9699328);
  f16*   vtb  = (f16*)(ws + 18087936);
  bf16*  attn = (bf16*)(ws + 26476544);   // partial O (z=0)
  bf16*  x1b  = (bf16*)(ws + 34865152);
  bf16*  hbuf = (bf16*)(ws + 1310720);    // aliases qb/kb/vtb (dead by FFN1)
  bf16*  xb   = (bf16*)(ws + 34865152);   // aliases x1b (dead after QKV GEMM)
  bf16*  po1  = (bf16*)(ws + 43253760);   // partial O (z=1)
  float* pden = (float*)(ws + 51642368);  // denominators [2][16][4096] f32

  cvt_w_kernel<<<2208, 256, 0, stream>>>(qkv_w, qwt, proj_w, pwt,
                                         ffn_w1, f1wt, ffn_w2, f2wt, x, xb);
  gemm_qkv_kernel<<<dim3(6, 128), 256, 0, stream>>>(xb, qwt, qkv_b, qb, kb, vtb);
  attn_kernel<<<dim3(32, 16, 2), 256, 0, stream>>>(qb, kb, vtb, attn, po1, pden);
  gemm_ln_kernel<4, true, false, false, true><<<512, 256, 0, stream>>>(
      attn, po1, pden, pwt, proj_b, x, n1_w, n1_b, nullptr, x1b);
  gemm_ffn1_kernel<<<dim3(6, 128), 256, 0, stream>>>(x1b, f1wt, ffn_b1, hbuf);
  gemm_ln_kernel<12, false, true, true, false><<<512, 256, 0, stream>>>(
      hbuf, nullptr, nullptr, f2wt, ffn_b2, x1b, n2_w, n2_b, out, nullptr);
}

// Round 4
// 236.730 us; speedup vs baseline: 1.4372x; 1.4372x over previous
//
#include <hip/hip_runtime.h>
#include <cstdint>
#include <cstddef>

typedef __bf16 bf16;
typedef __bf16 bf16x8 __attribute__((ext_vector_type(8)));
typedef __bf16 bf16x4 __attribute__((ext_vector_type(4)));
typedef _Float16 f16;
typedef _Float16 f16x4 __attribute__((ext_vector_type(4)));
typedef _Float16 f16x8 __attribute__((ext_vector_type(8)));
typedef __fp16 fp16x2 __attribute__((ext_vector_type(2)));
typedef float f32x4 __attribute__((ext_vector_type(4)));

#define DEV static __device__ __forceinline__
#if __has_builtin(__builtin_amdgcn_exp2f)
#define EXP2(x) __builtin_amdgcn_exp2f(x)
#else
#define EXP2(x) exp2f(x)
#endif
#define QSCALE 0.18033688011112042f

DEV float gelu_exact(float v) {
  return 0.5f * v * (1.0f + erff(v * 0.70710678118654752f));
}

// ---------------- coalesced weight transpose: W[K,N] fp32 -> Wt[N,K] bf16 ---
// blocks 0..159: 64x64 weight transpose tiles. blocks 160..2207: x fp32->bf16.
__global__ void cvt_w_kernel(const float* __restrict__ qkv_w, bf16* __restrict__ qwt,
                             const float* __restrict__ proj_w, bf16* __restrict__ pwt,
                             const float* __restrict__ f1w, bf16* __restrict__ f1wt,
                             const float* __restrict__ f2w, bf16* __restrict__ f2wt,
                             const float* __restrict__ x, bf16* __restrict__ xb) {
  int blk = blockIdx.x;
  const int tid = threadIdx.x;
  if (blk >= 160) {  // x conversion: 2048 blocks x 2048 elems
    const size_t i = ((size_t)(blk - 160) * 256 + tid) * 8;
    const float4 a0 = *(const float4*)(x + i);
    const float4 a1 = *(const float4*)(x + i + 4);
    bf16x8 v;
    v[0] = (bf16)a0.x; v[1] = (bf16)a0.y; v[2] = (bf16)a0.z; v[3] = (bf16)a0.w;
    v[4] = (bf16)a1.x; v[5] = (bf16)a1.y; v[6] = (bf16)a1.z; v[7] = (bf16)a1.w;
    *(bf16x8*)(xb + i) = v;
    return;
  }
  const float* w; bf16* o; int K, N;
  if (blk < 48)       { w = qkv_w;  o = qwt;  K = 256; N = 768; }
  else if (blk < 64)  { w = proj_w; o = pwt;  K = 256; N = 256; blk -= 48; }
  else if (blk < 112) { w = f1w;    o = f1wt; K = 256; N = 768; blk -= 64; }
  else                { w = f2w;    o = f2wt; K = 768; N = 256; blk -= 112; }
  const int ntiles = N >> 6;
  const int kt = blk / ntiles, nt = blk - kt * ntiles;
  const int k0 = kt * 64, n0 = nt * 64;
  __shared__ float tile[64][65];
#pragma unroll
  for (int j = 0; j < 4; ++j) {  // load: 1024 float4 chunks, coalesced rows
    const int c = j * 256 + tid;
    const int row = c >> 4, c4 = (c & 15) * 4;
    const float4 v = *(const float4*)(w + (size_t)(k0 + row) * N + n0 + c4);
    tile[row][c4] = v.x; tile[row][c4 + 1] = v.y;
    tile[row][c4 + 2] = v.z; tile[row][c4 + 3] = v.w;
  }
  __syncthreads();
#pragma unroll
  for (int j = 0; j < 4; ++j) {  // store: 1024 bf16x4 chunks, coalesced rows
    const int c = j * 256 + tid;
    const int n = c >> 4, k4 = (c & 15) * 4;
    bf16x4 ov;
#pragma unroll
    for (int i = 0; i < 4; ++i) ov[i] = (bf16)tile[k4 + i][n];
    *(bf16x4*)(o + (size_t)(n0 + n) * K + k0 + k4) = ov;
  }
}

// ---------------- QKV GEMM (bf16 A, pre-converted) --------------------------
__global__ __launch_bounds__(256, 3)
void gemm_qkv_kernel(const bf16* __restrict__ A, const bf16* __restrict__ Wt,
                     const float* __restrict__ bias, bf16* __restrict__ qb,
                     bf16* __restrict__ kb, f16* __restrict__ vt) {
  const int tid = threadIdx.x;
  const int wave = tid >> 6, lane = tid & 63;
  const int quad = lane >> 4, l15 = lane & 15;
  const int m0 = blockIdx.y * 128, n0 = blockIdx.x * 128;
  const int mw = (wave >> 1) * 64, nw = (wave & 1) * 64;
  const int K = 256;

  __shared__ bf16 lA[128 * 72];
  __shared__ bf16 lB[128 * 72];

  f32x4 acc[4][4] = {};

  for (int k0 = 0; k0 < K; k0 += 64) {
#pragma unroll
    for (int j = 0; j < 4; ++j) {
      const int c = j * 256 + tid;
      const int row = c >> 3, kc = (c & 7) * 8;
      *(uint4*)(lA + row * 72 + kc) =
          *(const uint4*)(A + (size_t)(m0 + row) * K + k0 + kc);
      *(uint4*)(lB + row * 72 + kc) =
          *(const uint4*)(Wt + (size_t)(n0 + row) * K + k0 + kc);
    }
    __syncthreads();
#pragma unroll
    for (int ks = 0; ks < 2; ++ks) {
      bf16x8 af[4], bfm[4];
#pragma unroll
      for (int i = 0; i < 4; ++i)
        af[i] = *(const bf16x8*)(lA + (mw + i * 16 + l15) * 72 + ks * 32 + quad * 8);
#pragma unroll
      for (int j = 0; j < 4; ++j)
        bfm[j] = *(const bf16x8*)(lB + (nw + j * 16 + l15) * 72 + ks * 32 + quad * 8);
#pragma unroll
      for (int i = 0; i < 4; ++i)
#pragma unroll
        for (int j = 0; j < 4; ++j)
          acc[i][j] = __builtin_amdgcn_mfma_f32_16x16x32_bf16(af[i], bfm[j],
                                                              acc[i][j], 0, 0, 0);
    }
    __syncthreads();
  }

  const bool isV = (n0 >= 512);
#pragma unroll
  for (int i = 0; i < 4; ++i) {
#pragma unroll
    for (int j = 0; j < 4; ++j) {
      const int n = n0 + nw + j * 16 + l15;
      const float bs = bias[n];
      if (isV) {
        const int m = m0 + mw + i * 16 + quad * 4;
        const int b = m >> 12, t = m & 4095;
        const int h = (n >> 6) & 3, d = n & 63;
        const int tp = (t & ~31) | (((t >> 2) & 3) << 3) | (((t >> 4) & 1) << 2);
        f16x4 hv;
#pragma unroll
        for (int r = 0; r < 4; ++r) hv[r] = (f16)(acc[i][j][r] + bs);
        *(f16x4*)(vt + (size_t)((b * 4 + h) * 64 + d) * 4096 + tp) = hv;
      } else {
        const int s = n >> 8, cc = n & 255, h = cc >> 6, d = cc & 63;
#pragma unroll
        for (int r = 0; r < 4; ++r) {
          const int m = m0 + mw + i * 16 + quad * 4 + r;
          const int b = m >> 12, t = m & 4095;
          const float v = acc[i][j][r] + bs;
          const size_t idx = (size_t)((b * 4 + h) * 4096 + t) * 64 + d;
          if (s == 0) qb[idx] = (bf16)(v * QSCALE);
          else        kb[idx] = (bf16)v;
        }
      }
    }
  }
}

// ---------------- flash attention: KV-split (z=2), R2 structure -------------
__global__ __launch_bounds__(256, 2)
void attn_kernel(const bf16* __restrict__ q, const bf16* __restrict__ k,
                 const f16* __restrict__ vt, bf16* __restrict__ o0,
                 bf16* __restrict__ o1, float* __restrict__ pD) {
  const int tid = threadIdx.x;
  const int wave = tid >> 6, lane = tid & 63;
  const int quad = lane >> 4, l15 = lane & 15;
  const int bh = blockIdx.y;
  const int q0 = blockIdx.x * 128;
  const int z = blockIdx.z;
  const int kvbase = z * 2048;
  __shared__ bf16 lK[2][64 * 72];
  __shared__ f16  lV[2][64 * 72];

  bf16x8 qa0[2], qa1[2];
#pragma unroll
  for (int s = 0; s < 2; ++s) {
    const bf16* qp =
        q + ((size_t)bh * 4096 + q0 + wave * 32 + s * 16 + l15) * 64 + quad * 8;
    qa0[s] = *(const bf16x8*)(qp);
    qa1[s] = *(const bf16x8*)(qp + 32);
  }

  const int row0 = tid >> 3, off = (tid & 7) * 8;
  const bf16* kp = k + ((size_t)bh * 4096 + kvbase + row0) * 64 + off;
  const f16*  vp = vt + ((size_t)bh * 64 + row0) * 4096 + kvbase + off;
  const int lidx = row0 * 72 + off;

  *(uint4*)(lK[0] + lidx)            = *(const uint4*)(kp);
  *(uint4*)(lK[0] + lidx + 32 * 72)  = *(const uint4*)(kp + 32 * 64);
  *(uint4*)(lV[0] + lidx)            = *(const uint4*)(vp);
  *(uint4*)(lV[0] + lidx + 32 * 72)  = *(const uint4*)(vp + 32 * 4096);

  f32x4 accO[2][4] = {};
  f32x4 accD[2] = {};
  const f16x8 vone8 = {(f16)1.0f, (f16)1.0f, (f16)1.0f, (f16)1.0f,
                       (f16)1.0f, (f16)1.0f, (f16)1.0f, (f16)1.0f};
  uint4 pk0, pk1, pv0, pv1;

  for (int it = 0; it < 32; ++it) {
    const int cur = it & 1;
    if (it + 1 < 32) {
      const bf16* kn = kp + (size_t)(it + 1) * 64 * 64;
      const f16*  vn = vp + (it + 1) * 64;
      pk0 = *(const uint4*)(kn);
      pk1 = *(const uint4*)(kn + 32 * 64);
      pv0 = *(const uint4*)(vn);
      pv1 = *(const uint4*)(vn + 32 * 4096);
    }
    __syncthreads();

    f32x4 sf[2][4];
    __builtin_amdgcn_s_setprio(1);
#pragma unroll
    for (int c = 0; c < 4; ++c) {
      const bf16x8 kb0 = *(const bf16x8*)(lK[cur] + (c * 16 + l15) * 72 + quad * 8);
      const bf16x8 kb1 = *(const bf16x8*)(lK[cur] + (c * 16 + l15) * 72 + 32 + quad * 8);
#pragma unroll
      for (int s = 0; s < 2; ++s) {
        f32x4 t = {};
        t = __builtin_amdgcn_mfma_f32_16x16x32_bf16(kb0, qa0[s], t, 0, 0, 0);
        t = __builtin_amdgcn_mfma_f32_16x16x32_bf16(kb1, qa1[s], t, 0, 0, 0);
        sf[s][c] = t;
      }
    }
    __builtin_amdgcn_s_setprio(0);

    f16x8 pa[2][2];
#pragma unroll
    for (int s = 0; s < 2; ++s)
#pragma unroll
      for (int c2 = 0; c2 < 2; ++c2) {
        union { fp16x2 h2[4]; f16x8 h8; } u;
        u.h2[0] = __builtin_amdgcn_cvt_pkrtz(EXP2(sf[s][2 * c2][0]),
                                             EXP2(sf[s][2 * c2][1]));
        u.h2[1] = __builtin_amdgcn_cvt_pkrtz(EXP2(sf[s][2 * c2][2]),
                                             EXP2(sf[s][2 * c2][3]));
        u.h2[2] = __builtin_amdgcn_cvt_pkrtz(EXP2(sf[s][2 * c2 + 1][0]),
                                             EXP2(sf[s][2 * c2 + 1][1]));
        u.h2[3] = __builtin_amdgcn_cvt_pkrtz(EXP2(sf[s][2 * c2 + 1][2]),
                                             EXP2(sf[s][2 * c2 + 1][3]));
        pa[s][c2] = u.h8;
      }

    __builtin_amdgcn_s_setprio(1);
#pragma unroll
    for (int s = 0; s < 2; ++s)
#pragma unroll
      for (int c2 = 0; c2 < 2; ++c2)
        accD[s] = __builtin_amdgcn_mfma_f32_16x16x32_f16(pa[s][c2], vone8,
                                                         accD[s], 0, 0, 0);

#pragma unroll
    for (int c2 = 0; c2 < 2; ++c2) {
#pragma unroll
      for (int n = 0; n < 4; ++n) {
        const f16x8 vb =
            *(const f16x8*)(lV[cur] + (n * 16 + l15) * 72 + c2 * 32 + quad * 8);
#pragma unroll
        for (int s = 0; s < 2; ++s)
          accO[s][n] = __builtin_amdgcn_mfma_f32_16x16x32_f16(pa[s][c2], vb,
                                                              accO[s][n], 0, 0, 0);
      }
    }
    __builtin_amdgcn_s_setprio(0);

    if (it + 1 < 32) {
      *(uint4*)(lK[cur ^ 1] + lidx)           = pk0;
      *(uint4*)(lK[cur ^ 1] + lidx + 32 * 72) = pk1;
      *(uint4*)(lV[cur ^ 1] + lidx)           = pv0;
      *(uint4*)(lV[cur ^ 1] + lidx + 32 * 72) = pv1;
    }
  }

  bf16* po = z ? o1 : o0;
  const int b = bh >> 2, h = bh & 3;
#pragma unroll
  for (int s = 0; s < 2; ++s) {
    float inv[4];
#pragma unroll
    for (int r = 0; r < 4; ++r) inv[r] = 1.0f / accD[s][r];
#pragma unroll
    for (int r = 0; r < 4; ++r) {
      const int t = q0 + wave * 32 + s * 16 + quad * 4 + r;
      if (l15 == 0) pD[(size_t)(z * 16 + bh) * 4096 + t] = accD[s][r];
#pragma unroll
      for (int n = 0; n < 4; ++n)
        po[(size_t)(b * 4096 + t) * 256 + h * 64 + n * 16 + l15] =
            (bf16)(accO[s][n][r] * inv[r]);
    }
  }
}

// ---------------- FFN1: bf16-A GEMM + gelu ----------------------------------
__global__ __launch_bounds__(256, 3)
void gemm_ffn1_kernel(const bf16* __restrict__ A, const bf16* __restrict__ Wt,
                      const float* __restrict__ bias, bf16* __restrict__ ob) {
  const int tid = threadIdx.x;
  const int wave = tid >> 6, lane = tid & 63;
  const int quad = lane >> 4, l15 = lane & 15;
  const int m0 = blockIdx.y * 128, n0 = blockIdx.x * 128;
  const int mw = (wave >> 1) * 64, nw = (wave & 1) * 64;
  const int K = 256;

  __shared__ bf16 lA[128 * 72];
  __shared__ bf16 lB[128 * 72];

  f32x4 acc[4][4] = {};

  for (int k0 = 0; k0 < K; k0 += 64) {
#pragma unroll
    for (int j = 0; j < 4; ++j) {
      const int c = j * 256 + tid;
      const int row = c >> 3, kc = (c & 7) * 8;
      *(uint4*)(lA + row * 72 + kc) =
          *(const uint4*)(A + (size_t)(m0 + row) * K + k0 + kc);
      *(uint4*)(lB + row * 72 + kc) =
          *(const uint4*)(Wt + (size_t)(n0 + row) * K + k0 + kc);
    }
    __syncthreads();
#pragma unroll
    for (int ks = 0; ks < 2; ++ks) {
      bf16x8 af[4], bfm[4];
#pragma unroll
      for (int i = 0; i < 4; ++i)
        af[i] = *(const bf16x8*)(lA + (mw + i * 16 + l15) * 72 + ks * 32 + quad * 8);
#pragma unroll
      for (int j = 0; j < 4; ++j)
        bfm[j] = *(const bf16x8*)(lB + (nw + j * 16 + l15) * 72 + ks * 32 + quad * 8);
#pragma unroll
      for (int i = 0; i < 4; ++i)
#pragma unroll
        for (int j = 0; j < 4; ++j)
          acc[i][j] = __builtin_amdgcn_mfma_f32_16x16x32_bf16(af[i], bfm[j],
                                                              acc[i][j], 0, 0, 0);
    }
    __syncthreads();
  }

#pragma unroll
  for (int i = 0; i < 4; ++i) {
#pragma unroll
    for (int j = 0; j < 4; ++j) {
      const int n = n0 + nw + j * 16 + l15;
      const float bs = bias[n];
#pragma unroll
      for (int r = 0; r < 4; ++r) {
        const int m = m0 + mw + i * 16 + quad * 4 + r;
        ob[(size_t)m * 768 + n] = (bf16)gelu_exact(acc[i][j][r] + bs);
      }
    }
  }
}

// ---------------- GEMM + bias + residual + LayerNorm fused ------------------
// 32-row x 256-col tile (full LN rows), grid M/32 = 512.
// COMBINE: A = denominator-weighted average of two attention partials,
// blended inline during the A-staging phase (no combine kernel).
template <int KTILES, bool COMBINE, bool RESID_BF16, bool WRITE_F, bool WRITE_B>
__global__ __launch_bounds__(256, 3)
void gemm_ln_kernel(const bf16* __restrict__ A, const bf16* __restrict__ A2,
                    const float* __restrict__ pD, const bf16* __restrict__ Wt,
                    const float* __restrict__ bias, const void* __restrict__ Rv,
                    const float* __restrict__ lw, const float* __restrict__ lb,
                    float* __restrict__ outf, bf16* __restrict__ outb) {
  const int tid = threadIdx.x;
  const int wave = tid >> 6, lane = tid & 63;
  const int quad = lane >> 4, l15 = lane & 15;
  const int m0 = blockIdx.x * 32;
  const int nw = wave * 64;
  const int K = KTILES * 64;
  __shared__ bf16 lA[32 * 72];
  __shared__ bf16 lB[256 * 72];
  __shared__ float lnsum[4][32];
  __shared__ float lnsq[4][32];
  __shared__ float lnstat[32][2];
  f32x4 acc[2][4] = {};

  for (int kt = 0; kt < KTILES; ++kt) {
    const int k0 = kt * 64;
    {
      const int row = tid >> 3, kc = (tid & 7) * 8;
      const int am = m0 + row;
      if constexpr (COMBINE) {
        const int h = (k0 + kc) >> 6;  // == kt for K=256
        const int ab = am >> 12, at = am & 4095;
        const float d0 = pD[(size_t)(ab * 4 + h) * 4096 + at];
        const float d1 = pD[(size_t)(16 + ab * 4 + h) * 4096 + at];
        const float wsum = 1.0f / (d0 + d1);
        const float w0 = d0 * wsum, w1 = d1 * wsum;
        const bf16x8 a0 = *(const bf16x8*)(A  + (size_t)am * K + k0 + kc);
        const bf16x8 a1 = *(const bf16x8*)(A2 + (size_t)am * K + k0 + kc);
        bf16x8 cv;
#pragma unroll
        for (int i = 0; i < 8; ++i)
          cv[i] = (bf16)((float)a0[i] * w0 + (float)a1[i] * w1);
        *(bf16x8*)(lA + row * 72 + kc) = cv;
      } else {
        *(uint4*)(lA + row * 72 + kc) =
            *(const uint4*)(A + (size_t)am * K + k0 + kc);
      }
    }
#pragma unroll
    for (int j = 0; j < 8; ++j) {
      const int c = j * 256 + tid;
      const int row = c >> 3, kc = (c & 7) * 8;
      *(uint4*)(lB + row * 72 + kc) =
          *(const uint4*)(Wt + (size_t)row * K + k0 + kc);
    }
    __syncthreads();
#pragma unroll
    for (int ks = 0; ks < 2; ++ks) {
      bf16x8 af[2], bfm[4];
#pragma unroll
      for (int i = 0; i < 2; ++i)
        af[i] = *(const bf16x8*)(lA + (i * 16 + l15) * 72 + ks * 32 + quad * 8);
#pragma unroll
      for (int j = 0; j < 4; ++j)
        bfm[j] = *(const bf16x8*)(lB + (nw + j * 16 + l15) * 72 + ks * 32 + quad * 8);
#pragma unroll
      for (int i = 0; i < 2; ++i)
#pragma unroll
        for (int j = 0; j < 4; ++j)
          acc[i][j] = __builtin_amdgcn_mfma_f32_16x16x32_bf16(af[i], bfm[j],
                                                              acc[i][j], 0, 0, 0);
    }
    __syncthreads();
  }

  float bv[4], lwv[4], lbv[4];
#pragma unroll
  for (int j = 0; j < 4; ++j) {
    const int col = nw + 16 * j + l15;
    bv[j] = bias[col]; lwv[j] = lw[col]; lbv[j] = lb[col];
  }
#pragma unroll
  for (int i = 0; i < 2; ++i) {
    float ps[4] = {}, pq[4] = {};
#pragma unroll
    for (int j = 0; j < 4; ++j) {
#pragma unroll
      for (int r = 0; r < 4; ++r) {
        const int m = m0 + 16 * i + 4 * quad + r;
        const size_t ri = (size_t)m * 256 + nw + 16 * j + l15;
        const float rv = RESID_BF16 ? (float)((const bf16*)Rv)[ri]
                                    : ((const float*)Rv)[ri];
        const float v = acc[i][j][r] + bv[j] + rv;
        acc[i][j][r] = v;
        ps[r] += v;
        pq[r] += v * v;
      }
    }
#pragma unroll
    for (int r = 0; r < 4; ++r) {
#pragma unroll
      for (int mm = 1; mm < 16; mm <<= 1) {
        ps[r] += __shfl_xor(ps[r], mm, 64);
        pq[r] += __shfl_xor(pq[r], mm, 64);
      }
      if (l15 == 0) {
        lnsum[wave][16 * i + 4 * quad + r] = ps[r];
        lnsq[wave][16 * i + 4 * quad + r] = pq[r];
      }
    }
  }
  __syncthreads();
  if (tid < 32) {
    const float s = lnsum[0][tid] + lnsum[1][tid] + lnsum[2][tid] + lnsum[3][tid];
    const float sq = lnsq[0][tid] + lnsq[1][tid] + lnsq[2][tid] + lnsq[3][tid];
    const float mean = s * (1.0f / 256.0f);
    const float var = sq * (1.0f / 256.0f) - mean * mean;
    lnstat[tid][0] = mean;
    lnstat[tid][1] = rsqrtf(var + 1e-5f);
  }
  __syncthreads();
#pragma unroll
  for (int i = 0; i < 2; ++i) {
#pragma unroll
    for (int r = 0; r < 4; ++r) {
      const int row = 16 * i + 4 * quad + r;
      const float mean = lnstat[row][0], rstd = lnstat[row][1];
#pragma unroll
      for (int j = 0; j < 4; ++j) {
        const float ov = (acc[i][j][r] - mean) * rstd * lwv[j] + lbv[j];
        const size_t gi = (size_t)(m0 + row) * 256 + nw + 16 * j + l15;
        if constexpr (WRITE_F) outf[gi] = ov;
        if constexpr (WRITE_B) outb[gi] = (bf16)ov;
      }
    }
  }
}

extern "C" void kernel_launch(void* const* d_in, const int* in_sizes, int n_in,
                              void* d_out, int out_size, void* d_ws, size_t ws_size,
                              hipStream_t stream) {
  const float* x      = (const float*)d_in[0];
  const float* qkv_w  = (const float*)d_in[1];
  const float* qkv_b  = (const float*)d_in[2];
  const float* proj_w = (const float*)d_in[3];
  const float* proj_b = (const float*)d_in[4];
  const float* n1_w   = (const float*)d_in[5];
  const float* n1_b   = (const float*)d_in[6];
  const float* ffn_w1 = (const float*)d_in[7];
  const float* ffn_b1 = (const float*)d_in[8];
  const float* ffn_w2 = (const float*)d_in[9];
  const float* ffn_b2 = (const float*)d_in[10];
  const float* n2_w   = (const float*)d_in[11];
  const float* n2_b   = (const float*)d_in[12];
  float* out = (float*)d_out;

  char* ws = (char*)d_ws;
  bf16*  qwt  = (bf16*)(ws + 0);
  bf16*  pwt  = (bf16*)(ws + 393216);
  bf16*  f1wt = (bf16*)(ws + 524288);
  bf16*  f2wt = (bf16*)(ws + 917504);
  bf16*  qb   = (bf16*)(ws + 1310720);
  bf16*  kb   = (bf16*)(ws + 9699328);
  f16*   vtb  = (f16*)(ws + 18087936);
  bf16*  attn = (bf16*)(ws + 26476544);   // partial O (z=0)
  bf16*  x1b  = (bf16*)(ws + 34865152);
  bf16*  hbuf = (bf16*)(ws + 1310720);    // aliases qb/kb/vtb (dead by FFN1)
  bf16*  xb   = (bf16*)(ws + 34865152);   // aliases x1b (dead after QKV GEMM)
  bf16*  po1  = (bf16*)(ws + 43253760);   // partial O (z=1)
  float* pden = (float*)(ws + 51642368);  // denominators [2][16][4096] f32

  cvt_w_kernel<<<2208, 256, 0, stream>>>(qkv_w, qwt, proj_w, pwt,
                                         ffn_w1, f1wt, ffn_w2, f2wt, x, xb);
  gemm_qkv_kernel<<<dim3(6, 128), 256, 0, stream>>>(xb, qwt, qkv_b, qb, kb, vtb);
  attn_kernel<<<dim3(32, 16, 2), 256, 0, stream>>>(qb, kb, vtb, attn, po1, pden);
  gemm_ln_kernel<4, true, false, false, true><<<512, 256, 0, stream>>>(
      attn, po1, pden, pwt, proj_b, x, n1_w, n1_b, nullptr, x1b);
  gemm_ffn1_kernel<<<dim3(6, 128), 256, 0, stream>>>(x1b, f1wt, ffn_b1, hbuf);
  gemm_ln_kernel<12, false, true, true, false><<<512, 256, 0, stream>>>(
      hbuf, nullptr, nullptr, f2wt, ffn_b2, x1b, n2_w, n2_b, out, nullptr);
}

// Round 5
// 228.147 us; speedup vs baseline: 1.4913x; 1.0376x over previous
//
#include <hip/hip_runtime.h>
#include <cstdint>
#include <cstddef>

typedef __bf16 bf16;
typedef __bf16 bf16x8 __attribute__((ext_vector_type(8)));
typedef __bf16 bf16x4 __attribute__((ext_vector_type(4)));
typedef _Float16 f16;
typedef _Float16 f16x4 __attribute__((ext_vector_type(4)));
typedef _Float16 f16x8 __attribute__((ext_vector_type(8)));
typedef __fp16 fp16x2 __attribute__((ext_vector_type(2)));
typedef float f32x4 __attribute__((ext_vector_type(4)));

#define DEV static __device__ __forceinline__
#if __has_builtin(__builtin_amdgcn_exp2f)
#define EXP2(x) __builtin_amdgcn_exp2f(x)
#else
#define EXP2(x) exp2f(x)
#endif
#define QSCALE 0.18033688011112042f

DEV float gelu_exact(float v) {
  return 0.5f * v * (1.0f + erff(v * 0.70710678118654752f));
}

// ---- gload_lds staging into linear [ROWS][64]-bf16 LDS tile with chunk
// swizzle c' = c ^ (r&7). Source row-major, stride ldK elems, base (row0,k0).
// Inverse-swizzled SOURCE + swizzled READ (rule 21); LDS dest stays linear.
template <int ROWS>
DEV void stage_swz(bf16* lbase, const bf16* g, int ldK) {
  const int tid = threadIdx.x;
  const int wave = tid >> 6, lane = tid & 63;
  const int r8 = lane >> 3;                 // row within 8-row chunk
  const int c = (lane & 7) ^ r8;            // fetch inverse-swizzled chunk
  const size_t goff = (size_t)r8 * ldK + c * 8;
#pragma unroll
  for (int ch = wave; ch < (ROWS >> 3); ch += 4) {
    __builtin_amdgcn_global_load_lds(
        (const __attribute__((address_space(1))) void*)(g + (size_t)ch * 8 * ldK + goff),
        (__attribute__((address_space(3))) void*)(lbase + ch * 512), 16, 0, 0);
  }
}

// fragment address in swizzled linear tile: row R, logical 16B chunk c (0..7)
DEV int swzi(int R, int c) { return R * 64 + ((c ^ (R & 7)) << 3); }

// ---------------- coalesced weight transpose: W[K,N] fp32 -> Wt[N,K] bf16 ---
// blocks 0..159: 64x64 weight transpose tiles. blocks 160..2207: x fp32->bf16.
__global__ void cvt_w_kernel(const float* __restrict__ qkv_w, bf16* __restrict__ qwt,
                             const float* __restrict__ proj_w, bf16* __restrict__ pwt,
                             const float* __restrict__ f1w, bf16* __restrict__ f1wt,
                             const float* __restrict__ f2w, bf16* __restrict__ f2wt,
                             const float* __restrict__ x, bf16* __restrict__ xb) {
  int blk = blockIdx.x;
  const int tid = threadIdx.x;
  if (blk >= 160) {  // x conversion: 2048 blocks x 2048 elems
    const size_t i = ((size_t)(blk - 160) * 256 + tid) * 8;
    const float4 a0 = *(const float4*)(x + i);
    const float4 a1 = *(const float4*)(x + i + 4);
    bf16x8 v;
    v[0] = (bf16)a0.x; v[1] = (bf16)a0.y; v[2] = (bf16)a0.z; v[3] = (bf16)a0.w;
    v[4] = (bf16)a1.x; v[5] = (bf16)a1.y; v[6] = (bf16)a1.z; v[7] = (bf16)a1.w;
    *(bf16x8*)(xb + i) = v;
    return;
  }
  const float* w; bf16* o; int K, N;
  if (blk < 48)       { w = qkv_w;  o = qwt;  K = 256; N = 768; }
  else if (blk < 64)  { w = proj_w; o = pwt;  K = 256; N = 256; blk -= 48; }
  else if (blk < 112) { w = f1w;    o = f1wt; K = 256; N = 768; blk -= 64; }
  else                { w = f2w;    o = f2wt; K = 768; N = 256; blk -= 112; }
  const int ntiles = N >> 6;
  const int kt = blk / ntiles, nt = blk - kt * ntiles;
  const int k0 = kt * 64, n0 = nt * 64;
  __shared__ float tile[64][65];
#pragma unroll
  for (int j = 0; j < 4; ++j) {  // load: 1024 float4 chunks, coalesced rows
    const int c = j * 256 + tid;
    const int row = c >> 4, c4 = (c & 15) * 4;
    const float4 v = *(const float4*)(w + (size_t)(k0 + row) * N + n0 + c4);
    tile[row][c4] = v.x; tile[row][c4 + 1] = v.y;
    tile[row][c4 + 2] = v.z; tile[row][c4 + 3] = v.w;
  }
  __syncthreads();
#pragma unroll
  for (int j = 0; j < 4; ++j) {  // store: 1024 bf16x4 chunks, coalesced rows
    const int c = j * 256 + tid;
    const int n = c >> 4, k4 = (c & 15) * 4;
    bf16x4 ov;
#pragma unroll
    for (int i = 0; i < 4; ++i) ov[i] = (bf16)tile[k4 + i][n];
    *(bf16x4*)(o + (size_t)(n0 + n) * K + k0 + k4) = ov;
  }
}

// ---------------- QKV GEMM (bf16 A), gload_lds staging ----------------------
__global__ __launch_bounds__(256, 3)
void gemm_qkv_kernel(const bf16* __restrict__ A, const bf16* __restrict__ Wt,
                     const float* __restrict__ bias, bf16* __restrict__ qb,
                     bf16* __restrict__ kb, f16* __restrict__ vt) {
  const int tid = threadIdx.x;
  const int wave = tid >> 6, lane = tid & 63;
  const int quad = lane >> 4, l15 = lane & 15;
  const int m0 = blockIdx.y * 128, n0 = blockIdx.x * 128;
  const int mw = (wave >> 1) * 64, nw = (wave & 1) * 64;
  const int K = 256;

  __shared__ bf16 lA[128 * 64];
  __shared__ bf16 lB[128 * 64];

  f32x4 acc[4][4] = {};

  for (int k0 = 0; k0 < K; k0 += 64) {
    stage_swz<128>(lA, A + (size_t)m0 * K + k0, K);
    stage_swz<128>(lB, Wt + (size_t)n0 * K + k0, K);
    __syncthreads();
#pragma unroll
    for (int ks = 0; ks < 2; ++ks) {
      bf16x8 af[4], bfm[4];
#pragma unroll
      for (int i = 0; i < 4; ++i)
        af[i] = *(const bf16x8*)(lA + swzi(mw + i * 16 + l15, ks * 4 + quad));
#pragma unroll
      for (int j = 0; j < 4; ++j)
        bfm[j] = *(const bf16x8*)(lB + swzi(nw + j * 16 + l15, ks * 4 + quad));
#pragma unroll
      for (int i = 0; i < 4; ++i)
#pragma unroll
        for (int j = 0; j < 4; ++j)
          acc[i][j] = __builtin_amdgcn_mfma_f32_16x16x32_bf16(af[i], bfm[j],
                                                              acc[i][j], 0, 0, 0);
    }
    __syncthreads();
  }

  const bool isV = (n0 >= 512);
#pragma unroll
  for (int i = 0; i < 4; ++i) {
#pragma unroll
    for (int j = 0; j < 4; ++j) {
      const int n = n0 + nw + j * 16 + l15;
      const float bs = bias[n];
      if (isV) {
        const int m = m0 + mw + i * 16 + quad * 4;
        const int b = m >> 12, t = m & 4095;
        const int h = (n >> 6) & 3, d = n & 63;
        const int tp = (t & ~31) | (((t >> 2) & 3) << 3) | (((t >> 4) & 1) << 2);
        f16x4 hv;
#pragma unroll
        for (int r = 0; r < 4; ++r) hv[r] = (f16)(acc[i][j][r] + bs);
        *(f16x4*)(vt + (size_t)((b * 4 + h) * 64 + d) * 4096 + tp) = hv;
      } else {
        const int s = n >> 8, cc = n & 255, h = cc >> 6, d = cc & 63;
#pragma unroll
        for (int r = 0; r < 4; ++r) {
          const int m = m0 + mw + i * 16 + quad * 4 + r;
          const int b = m >> 12, t = m & 4095;
          const float v = acc[i][j][r] + bs;
          const size_t idx = (size_t)((b * 4 + h) * 4096 + t) * 64 + d;
          if (s == 0) qb[idx] = (bf16)(v * QSCALE);
          else        kb[idx] = (bf16)v;
        }
      }
    }
  }
}

// ---------------- flash attention: KV-split (z=2), R2 structure -------------
__global__ __launch_bounds__(256, 2)
void attn_kernel(const bf16* __restrict__ q, const bf16* __restrict__ k,
                 const f16* __restrict__ vt, bf16* __restrict__ o0,
                 bf16* __restrict__ o1, float* __restrict__ pD) {
  const int tid = threadIdx.x;
  const int wave = tid >> 6, lane = tid & 63;
  const int quad = lane >> 4, l15 = lane & 15;
  const int bh = blockIdx.y;
  const int q0 = blockIdx.x * 128;
  const int z = blockIdx.z;
  const int kvbase = z * 2048;
  __shared__ bf16 lK[2][64 * 72];
  __shared__ f16  lV[2][64 * 72];

  bf16x8 qa0[2], qa1[2];
#pragma unroll
  for (int s = 0; s < 2; ++s) {
    const bf16* qp =
        q + ((size_t)bh * 4096 + q0 + wave * 32 + s * 16 + l15) * 64 + quad * 8;
    qa0[s] = *(const bf16x8*)(qp);
    qa1[s] = *(const bf16x8*)(qp + 32);
  }

  const int row0 = tid >> 3, off = (tid & 7) * 8;
  const bf16* kp = k + ((size_t)bh * 4096 + kvbase + row0) * 64 + off;
  const f16*  vp = vt + ((size_t)bh * 64 + row0) * 4096 + kvbase + off;
  const int lidx = row0 * 72 + off;

  *(uint4*)(lK[0] + lidx)            = *(const uint4*)(kp);
  *(uint4*)(lK[0] + lidx + 32 * 72)  = *(const uint4*)(kp + 32 * 64);
  *(uint4*)(lV[0] + lidx)            = *(const uint4*)(vp);
  *(uint4*)(lV[0] + lidx + 32 * 72)  = *(const uint4*)(vp + 32 * 4096);

  f32x4 accO[2][4] = {};
  f32x4 accD[2] = {};
  const f16x8 vone8 = {(f16)1.0f, (f16)1.0f, (f16)1.0f, (f16)1.0f,
                       (f16)1.0f, (f16)1.0f, (f16)1.0f, (f16)1.0f};
  uint4 pk0, pk1, pv0, pv1;

  for (int it = 0; it < 32; ++it) {
    const int cur = it & 1;
    if (it + 1 < 32) {
      const bf16* kn = kp + (size_t)(it + 1) * 64 * 64;
      const f16*  vn = vp + (it + 1) * 64;
      pk0 = *(const uint4*)(kn);
      pk1 = *(const uint4*)(kn + 32 * 64);
      pv0 = *(const uint4*)(vn);
      pv1 = *(const uint4*)(vn + 32 * 4096);
    }
    __syncthreads();

    f32x4 sf[2][4];
    __builtin_amdgcn_s_setprio(1);
#pragma unroll
    for (int c = 0; c < 4; ++c) {
      const bf16x8 kb0 = *(const bf16x8*)(lK[cur] + (c * 16 + l15) * 72 + quad * 8);
      const bf16x8 kb1 = *(const bf16x8*)(lK[cur] + (c * 16 + l15) * 72 + 32 + quad * 8);
#pragma unroll
      for (int s = 0; s < 2; ++s) {
        f32x4 t = {};
        t = __builtin_amdgcn_mfma_f32_16x16x32_bf16(kb0, qa0[s], t, 0, 0, 0);
        t = __builtin_amdgcn_mfma_f32_16x16x32_bf16(kb1, qa1[s], t, 0, 0, 0);
        sf[s][c] = t;
      }
    }
    __builtin_amdgcn_s_setprio(0);

    f16x8 pa[2][2];
#pragma unroll
    for (int s = 0; s < 2; ++s)
#pragma unroll
      for (int c2 = 0; c2 < 2; ++c2) {
        union { fp16x2 h2[4]; f16x8 h8; } u;
        u.h2[0] = __builtin_amdgcn_cvt_pkrtz(EXP2(sf[s][2 * c2][0]),
                                             EXP2(sf[s][2 * c2][1]));
        u.h2[1] = __builtin_amdgcn_cvt_pkrtz(EXP2(sf[s][2 * c2][2]),
                                             EXP2(sf[s][2 * c2][3]));
        u.h2[2] = __builtin_amdgcn_cvt_pkrtz(EXP2(sf[s][2 * c2 + 1][0]),
                                             EXP2(sf[s][2 * c2 + 1][1]));
        u.h2[3] = __builtin_amdgcn_cvt_pkrtz(EXP2(sf[s][2 * c2 + 1][2]),
                                             EXP2(sf[s][2 * c2 + 1][3]));
        pa[s][c2] = u.h8;
      }

    __builtin_amdgcn_s_setprio(1);
#pragma unroll
    for (int s = 0; s < 2; ++s)
#pragma unroll
      for (int c2 = 0; c2 < 2; ++c2)
        accD[s] = __builtin_amdgcn_mfma_f32_16x16x32_f16(pa[s][c2], vone8,
                                                         accD[s], 0, 0, 0);

#pragma unroll
    for (int c2 = 0; c2 < 2; ++c2) {
#pragma unroll
      for (int n = 0; n < 4; ++n) {
        const f16x8 vb =
            *(const f16x8*)(lV[cur] + (n * 16 + l15) * 72 + c2 * 32 + quad * 8);
#pragma unroll
        for (int s = 0; s < 2; ++s)
          accO[s][n] = __builtin_amdgcn_mfma_f32_16x16x32_f16(pa[s][c2], vb,
                                                              accO[s][n], 0, 0, 0);
      }
    }
    __builtin_amdgcn_s_setprio(0);

    if (it + 1 < 32) {
      *(uint4*)(lK[cur ^ 1] + lidx)           = pk0;
      *(uint4*)(lK[cur ^ 1] + lidx + 32 * 72) = pk1;
      *(uint4*)(lV[cur ^ 1] + lidx)           = pv0;
      *(uint4*)(lV[cur ^ 1] + lidx + 32 * 72) = pv1;
    }
  }

  bf16* po = z ? o1 : o0;
  const int b = bh >> 2, h = bh & 3;
#pragma unroll
  for (int s = 0; s < 2; ++s) {
    float inv[4];
#pragma unroll
    for (int r = 0; r < 4; ++r) inv[r] = 1.0f / accD[s][r];
#pragma unroll
    for (int r = 0; r < 4; ++r) {
      const int t = q0 + wave * 32 + s * 16 + quad * 4 + r;
      if (l15 == 0) pD[(size_t)(z * 16 + bh) * 4096 + t] = accD[s][r];
#pragma unroll
      for (int n = 0; n < 4; ++n)
        po[(size_t)(b * 4096 + t) * 256 + h * 64 + n * 16 + l15] =
            (bf16)(accO[s][n][r] * inv[r]);
    }
  }
}

// ---------------- FFN1: bf16-A GEMM + gelu, gload_lds staging ---------------
__global__ __launch_bounds__(256, 3)
void gemm_ffn1_kernel(const bf16* __restrict__ A, const bf16* __restrict__ Wt,
                      const float* __restrict__ bias, bf16* __restrict__ ob) {
  const int tid = threadIdx.x;
  const int wave = tid >> 6, lane = tid & 63;
  const int quad = lane >> 4, l15 = lane & 15;
  const int m0 = blockIdx.y * 128, n0 = blockIdx.x * 128;
  const int mw = (wave >> 1) * 64, nw = (wave & 1) * 64;
  const int K = 256;

  __shared__ bf16 lA[128 * 64];
  __shared__ bf16 lB[128 * 64];

  f32x4 acc[4][4] = {};

  for (int k0 = 0; k0 < K; k0 += 64) {
    stage_swz<128>(lA, A + (size_t)m0 * K + k0, K);
    stage_swz<128>(lB, Wt + (size_t)n0 * K + k0, K);
    __syncthreads();
#pragma unroll
    for (int ks = 0; ks < 2; ++ks) {
      bf16x8 af[4], bfm[4];
#pragma unroll
      for (int i = 0; i < 4; ++i)
        af[i] = *(const bf16x8*)(lA + swzi(mw + i * 16 + l15, ks * 4 + quad));
#pragma unroll
      for (int j = 0; j < 4; ++j)
        bfm[j] = *(const bf16x8*)(lB + swzi(nw + j * 16 + l15, ks * 4 + quad));
#pragma unroll
      for (int i = 0; i < 4; ++i)
#pragma unroll
        for (int j = 0; j < 4; ++j)
          acc[i][j] = __builtin_amdgcn_mfma_f32_16x16x32_bf16(af[i], bfm[j],
                                                              acc[i][j], 0, 0, 0);
    }
    __syncthreads();
  }

#pragma unroll
  for (int i = 0; i < 4; ++i) {
#pragma unroll
    for (int j = 0; j < 4; ++j) {
      const int n = n0 + nw + j * 16 + l15;
      const float bs = bias[n];
#pragma unroll
      for (int r = 0; r < 4; ++r) {
        const int m = m0 + mw + i * 16 + quad * 4 + r;
        ob[(size_t)m * 768 + n] = (bf16)gelu_exact(acc[i][j][r] + bs);
      }
    }
  }
}

// ---------------- GEMM + bias + residual + LayerNorm fused ------------------
// 32-row x 256-col tile (full LN rows), grid M/32 = 512. gload_lds staging.
// COMBINE: A = denominator-weighted average of two attention partials,
// blended in regs and ds_written to the swizzled layout (same involution).
template <int KTILES, bool COMBINE, bool RESID_BF16, bool WRITE_F, bool WRITE_B>
__global__ __launch_bounds__(256, 3)
void gemm_ln_kernel(const bf16* __restrict__ A, const bf16* __restrict__ A2,
                    const float* __restrict__ pD, const bf16* __restrict__ Wt,
                    const float* __restrict__ bias, const void* __restrict__ Rv,
                    const float* __restrict__ lw, const float* __restrict__ lb,
                    float* __restrict__ outf, bf16* __restrict__ outb) {
  const int tid = threadIdx.x;
  const int wave = tid >> 6, lane = tid & 63;
  const int quad = lane >> 4, l15 = lane & 15;
  const int m0 = blockIdx.x * 32;
  const int nw = wave * 64;
  const int K = KTILES * 64;
  __shared__ bf16 lA[32 * 64];
  __shared__ bf16 lB[256 * 64];
  __shared__ float lnsum[4][32];
  __shared__ float lnsq[4][32];
  __shared__ float lnstat[32][2];
  f32x4 acc[2][4] = {};

  for (int kt = 0; kt < KTILES; ++kt) {
    const int k0 = kt * 64;
    if constexpr (COMBINE) {
      const int row = tid >> 3, cc = tid & 7;
      const int am = m0 + row;
      const int h = (k0 + cc * 8) >> 6;  // == kt for K=256
      const int ab = am >> 12, at = am & 4095;
      const float d0 = pD[(size_t)(ab * 4 + h) * 4096 + at];
      const float d1 = pD[(size_t)(16 + ab * 4 + h) * 4096 + at];
      const float wsum = 1.0f / (d0 + d1);
      const float w0 = d0 * wsum, w1 = d1 * wsum;
      const bf16x8 a0 = *(const bf16x8*)(A  + (size_t)am * K + k0 + cc * 8);
      const bf16x8 a1 = *(const bf16x8*)(A2 + (size_t)am * K + k0 + cc * 8);
      bf16x8 cv;
#pragma unroll
      for (int i = 0; i < 8; ++i)
        cv[i] = (bf16)((float)a0[i] * w0 + (float)a1[i] * w1);
      *(bf16x8*)(lA + swzi(row, cc)) = cv;
    } else {
      stage_swz<32>(lA, A + (size_t)m0 * K + k0, K);
    }
    stage_swz<256>(lB, Wt + k0, K);
    __syncthreads();
#pragma unroll
    for (int ks = 0; ks < 2; ++ks) {
      bf16x8 af[2], bfm[4];
#pragma unroll
      for (int i = 0; i < 2; ++i)
        af[i] = *(const bf16x8*)(lA + swzi(i * 16 + l15, ks * 4 + quad));
#pragma unroll
      for (int j = 0; j < 4; ++j)
        bfm[j] = *(const bf16x8*)(lB + swzi(nw + j * 16 + l15, ks * 4 + quad));
#pragma unroll
      for (int i = 0; i < 2; ++i)
#pragma unroll
        for (int j = 0; j < 4; ++j)
          acc[i][j] = __builtin_amdgcn_mfma_f32_16x16x32_bf16(af[i], bfm[j],
                                                              acc[i][j], 0, 0, 0);
    }
    __syncthreads();
  }

  float bv[4], lwv[4], lbv[4];
#pragma unroll
  for (int j = 0; j < 4; ++j) {
    const int col = nw + 16 * j + l15;
    bv[j] = bias[col]; lwv[j] = lw[col]; lbv[j] = lb[col];
  }
#pragma unroll
  for (int i = 0; i < 2; ++i) {
    float ps[4] = {}, pq[4] = {};
#pragma unroll
    for (int j = 0; j < 4; ++j) {
#pragma unroll
      for (int r = 0; r < 4; ++r) {
        const int m = m0 + 16 * i + 4 * quad + r;
        const size_t ri = (size_t)m * 256 + nw + 16 * j + l15;
        const float rv = RESID_BF16 ? (float)((const bf16*)Rv)[ri]
                                    : ((const float*)Rv)[ri];
        const float v = acc[i][j][r] + bv[j] + rv;
        acc[i][j][r] = v;
        ps[r] += v;
        pq[r] += v * v;
      }
    }
#pragma unroll
    for (int r = 0; r < 4; ++r) {
#pragma unroll
      for (int mm = 1; mm < 16; mm <<= 1) {
        ps[r] += __shfl_xor(ps[r], mm, 64);
        pq[r] += __shfl_xor(pq[r], mm, 64);
      }
      if (l15 == 0) {
        lnsum[wave][16 * i + 4 * quad + r] = ps[r];
        lnsq[wave][16 * i + 4 * quad + r] = pq[r];
      }
    }
  }
  __syncthreads();
  if (tid < 32) {
    const float s = lnsum[0][tid] + lnsum[1][tid] + lnsum[2][tid] + lnsum[3][tid];
    const float sq = lnsq[0][tid] + lnsq[1][tid] + lnsq[2][tid] + lnsq[3][tid];
    const float mean = s * (1.0f / 256.0f);
    const float var = sq * (1.0f / 256.0f) - mean * mean;
    lnstat[tid][0] = mean;
    lnstat[tid][1] = rsqrtf(var + 1e-5f);
  }
  __syncthreads();
#pragma unroll
  for (int i = 0; i < 2; ++i) {
#pragma unroll
    for (int r = 0; r < 4; ++r) {
      const int row = 16 * i + 4 * quad + r;
      const float mean = lnstat[row][0], rstd = lnstat[row][1];
#pragma unroll
      for (int j = 0; j < 4; ++j) {
        const float ov = (acc[i][j][r] - mean) * rstd * lwv[j] + lbv[j];
        const size_t gi = (size_t)(m0 + row) * 256 + nw + 16 * j + l15;
        if constexpr (WRITE_F) outf[gi] = ov;
        if constexpr (WRITE_B) outb[gi] = (bf16)ov;
      }
    }
  }
}

extern "C" void kernel_launch(void* const* d_in, const int* in_sizes, int n_in,
                              void* d_out, int out_size, void* d_ws, size_t ws_size,
                              hipStream_t stream) {
  const float* x      = (const float*)d_in[0];
  const float* qkv_w  = (const float*)d_in[1];
  const float* qkv_b  = (const float*)d_in[2];
  const float* proj_w = (const float*)d_in[3];
  const float* proj_b = (const float*)d_in[4];
  const float* n1_w   = (const float*)d_in[5];
  const float* n1_b   = (const float*)d_in[6];
  const float* ffn_w1 = (const float*)d_in[7];
  const float* ffn_b1 = (const float*)d_in[8];
  const float* ffn_w2 = (const float*)d_in[9];
  const float* ffn_b2 = (const float*)d_in[10];
  const float* n2_w   = (const float*)d_in[11];
  const float* n2_b   = (const float*)d_in[12];
  float* out = (float*)d_out;

  char* ws = (char*)d_ws;
  bf16*  qwt  = (bf16*)(ws + 0);
  bf16*  pwt  = (bf16*)(ws + 393216);
  bf16*  f1wt = (bf16*)(ws + 524288);
  bf16*  f2wt = (bf16*)(ws + 917504);
  bf16*  qb   = (bf16*)(ws + 1310720);
  bf16*  kb   = (bf16*)(ws + 9699328);
  f16*   vtb  = (f16*)(ws + 18087936);
  bf16*  attn = (bf16*)(ws + 26476544);   // partial O (z=0)
  bf16*  x1b  = (bf16*)(ws + 34865152);
  bf16*  hbuf = (bf16*)(ws + 1310720);    // aliases qb/kb/vtb (dead by FFN1)
  bf16*  xb   = (bf16*)(ws + 34865152);   // aliases x1b (dead after QKV GEMM)
  bf16*  po1  = (bf16*)(ws + 43253760);   // partial O (z=1)
  float* pden = (float*)(ws + 51642368);  // denominators [2][16][4096] f32

  cvt_w_kernel<<<2208, 256, 0, stream>>>(qkv_w, qwt, proj_w, pwt,
                                         ffn_w1, f1wt, ffn_w2, f2wt, x, xb);
  gemm_qkv_kernel<<<dim3(6, 128), 256, 0, stream>>>(xb, qwt, qkv_b, qb, kb, vtb);
  attn_kernel<<<dim3(32, 16, 2), 256, 0, stream>>>(qb, kb, vtb, attn, po1, pden);
  gemm_ln_kernel<4, true, false, false, true><<<512, 256, 0, stream>>>(
      attn, po1, pden, pwt, proj_b, x, n1_w, n1_b, nullptr, x1b);
  gemm_ffn1_kernel<<<dim3(6, 128), 256, 0, stream>>>(x1b, f1wt, ffn_b1, hbuf);
  gemm_ln_kernel<12, false, true, true, false><<<512, 256, 0, stream>>>(
      hbuf, nullptr, nullptr, f2wt, ffn_b2, x1b, n2_w, n2_b, out, nullptr);
}